// Round 13
// baseline (176.326 us; speedup 1.0000x reference)
//
#include <hip/hip_runtime.h>
#include <hip/hip_bf16.h>

#define F_IN 128
#define HC   128   // H1*C1
#define C1   64
#define F_OUT 7
#define H2S  8      // padded h2 row stride
#define BSH  9      // 512 nodes per bucket
#define BSZ  512
#define BINCH 8192  // edges per WG in binning
#define BCAP 12288  // bucket region capacity (mean ~8700, +~17 sigma)

typedef __attribute__((ext_vector_type(8))) short short8;
typedef __attribute__((ext_vector_type(4))) float f32x4;
typedef __attribute__((ext_vector_type(2))) float f32x2;

__device__ __forceinline__ ushort f2bf(float f) {
    uint u = __builtin_bit_cast(uint, f);
    u = (u + 0x7FFFu + ((u >> 16) & 1u)) >> 16;   // RNE
    return (ushort)u;
}

// fp8-permuted layout: byte b = h*64 + lr*4 + jj  <->  col c = 16*(4*h+jj) + lr
__device__ __forceinline__ int perm_col(int p_byte) {
    int slp = p_byte >> 3, j = p_byte & 7;
    int h = slp >> 3, sg = slp & 7;
    int lr = 2 * sg + (j >> 2), jj = j & 3;
    return 16 * (4 * h + jj) + lr;
}

// ---- k_cvt: blocks [0,64) W1 -> bf16 transposed+swizzled; [64] W2p/b1p ------
__global__ __launch_bounds__(256) void k_cvt(
    const float* __restrict__ W1, ushort* __restrict__ Wsw,
    const float* __restrict__ W2, const float* __restrict__ b1,
    float* __restrict__ W2p, float* __restrict__ b1p)
{
    int b = blockIdx.x, t = threadIdx.x;
    if (b < 64) {
        int i = b * 256 + t;                // 0..16383
        int k = i >> 7, n = i & 127;
        float v = W1[k * HC + n];
        int idx = n * 128 + (((k & ~7) ^ ((n & 7) << 3)) | (k & 7));
        Wsw[idx] = f2bf(v);
    } else {
        for (int i = t; i < 128 * F_OUT; i += 256) {
            int p = i / F_OUT, o = i - p * F_OUT;
            W2p[i] = W2[perm_col(p) * F_OUT + o];
        }
        if (t < 128) b1p[t] = b1[perm_col(t)];
    }
}

// ---- k_bingemm: blocks [0,NBIN) edge binning; [NBIN,...) GEMM1 MFMA ---------
__global__ __launch_bounds__(256) void k_bingemm(
    const int* __restrict__ ei, int E, int Etot, int NBIN,
    int* __restrict__ bcnt, uint* __restrict__ binned,
    const float* __restrict__ x, const ushort* __restrict__ Wsw,
    const float* __restrict__ a_src, const float* __restrict__ a_dst,
    unsigned char* __restrict__ h1p, float* __restrict__ as1, float* __restrict__ ad1,
    int N)
{
    __shared__ __align__(16) char smem[128 * 128 * 2];
    const int t = threadIdx.x;

    if ((int)blockIdx.x < NBIN) {
        // ---------------- edge binning (single pass, fixed-capacity) --------
        int* hist = (int*)smem;          // [256]
        int* base = hist + 256;          // [256]
        hist[t] = 0;
        __syncthreads();
        long c0 = (long)blockIdx.x * BINCH;
#pragma unroll
        for (int i = 0; i < BINCH / 256; ++i) {
            long e = c0 + t + i * 256;
            if (e < Etot) {
                int d = (e < E) ? ei[E + e] : (int)(e - E);
                atomicAdd(&hist[d >> BSH], 1);
            }
        }
        __syncthreads();
        base[t] = t * BCAP + ((hist[t] > 0) ? atomicAdd(&bcnt[t], hist[t]) : 0);
        __syncthreads();
#pragma unroll
        for (int i = 0; i < BINCH / 256; ++i) {
            long e = c0 + t + i * 256;
            if (e < Etot) {
                int s, d;
                if (e < E) { s = ei[e]; d = ei[E + e]; } else { s = (int)(e - E); d = s; }
                int bkt = d >> BSH;
                int pos = atomicAdd(&base[bkt], 1);
                if (pos < (bkt + 1) * BCAP)   // overflow guard (never for this data)
                    binned[pos] = ((uint)s << BSH) | (uint)(d & (BSZ - 1));
            }
        }
    } else {
        // ---------------- GEMM1 (bf16 MFMA, fused alphas, fp8 h1 out) -------
        ushort* Bs = (ushort*)smem;     // pre-swizzled [n][k] bf16
        const int w = t >> 6, l = t & 63;
        const int lr = l & 15, hi = l >> 4;
        const int n0 = (blockIdx.x - NBIN) * 64;

        {
            const uint4* src = (const uint4*)Wsw;
            uint4* dst = (uint4*)Bs;
#pragma unroll
            for (int it = 0; it < 8; ++it) dst[t + it * 256] = src[t + it * 256];
        }
        __syncthreads();

        f32x4 acc[8];
#pragma unroll
        for (int j = 0; j < 8; ++j) acc[j] = (f32x4){0.f, 0.f, 0.f, 0.f};

        int arow = n0 + w * 16 + lr;
        if (arow >= N) arow = N - 1;
        const float* aptr = x + (size_t)arow * F_IN + hi * 8;

#pragma unroll
        for (int kt = 0; kt < 4; ++kt) {
            float4 f0 = *(const float4*)(aptr + kt * 32);
            float4 f1 = *(const float4*)(aptr + kt * 32 + 4);
            short8 a;
            a[0] = (short)f2bf(f0.x); a[1] = (short)f2bf(f0.y);
            a[2] = (short)f2bf(f0.z); a[3] = (short)f2bf(f0.w);
            a[4] = (short)f2bf(f1.x); a[5] = (short)f2bf(f1.y);
            a[6] = (short)f2bf(f1.z); a[7] = (short)f2bf(f1.w);
#pragma unroll
            for (int j = 0; j < 8; ++j) {
                int rn = 16 * j + lr;
                int kidx = (kt * 32 + hi * 8) ^ ((rn & 7) << 3);
                short8 b = *(const short8*)(Bs + rn * 128 + kidx);
                acc[j] = __builtin_amdgcn_mfma_f32_16x16x32_bf16(a, b, acc[j], 0, 0, 0);
            }
        }

        float as_[8], ad_[8];
#pragma unroll
        for (int j = 0; j < 8; ++j) {
            int hd = j >> 2;
            int c = 16 * (j & 3) + lr;
            as_[j] = a_src[hd * C1 + c];
            ad_[j] = a_dst[hd * C1 + c];
        }
#pragma unroll
        for (int i = 0; i < 4; ++i) {
            int r = n0 + w * 16 + hi * 4 + i;
            float ps0 = 0, ps1 = 0, pd0 = 0, pd1 = 0;
#pragma unroll
            for (int j = 0; j < 4; ++j) { ps0 += acc[j][i] * as_[j]; pd0 += acc[j][i] * ad_[j]; }
#pragma unroll
            for (int j = 4; j < 8; ++j) { ps1 += acc[j][i] * as_[j]; pd1 += acc[j][i] * ad_[j]; }
#pragma unroll
            for (int off = 1; off <= 8; off <<= 1) {
                ps0 += __shfl_xor(ps0, off, 64);
                ps1 += __shfl_xor(ps1, off, 64);
                pd0 += __shfl_xor(pd0, off, 64);
                pd1 += __shfl_xor(pd1, off, 64);
            }
            if (r < N) {
                // head-split fp8 layout: head0 word at byte lr*4, head1 at 64+lr*4
                int w0 = 0, w1 = 0;
                w0 = __builtin_amdgcn_cvt_pk_fp8_f32(acc[0][i], acc[1][i], w0, false);
                w0 = __builtin_amdgcn_cvt_pk_fp8_f32(acc[2][i], acc[3][i], w0, true);
                w1 = __builtin_amdgcn_cvt_pk_fp8_f32(acc[4][i], acc[5][i], w1, false);
                w1 = __builtin_amdgcn_cvt_pk_fp8_f32(acc[6][i], acc[7][i], w1, true);
                *(uint*)(h1p + (size_t)r * HC + lr * 4)      = (uint)w0;
                *(uint*)(h1p + (size_t)r * HC + 64 + lr * 4) = (uint)w1;
                if (lr == 0) {
                    as1[r * 2 + 0] = ps0; as1[r * 2 + 1] = ps1;
                    ad1[r * 2 + 0] = pd0; ad1[r * 2 + 1] = pd1;
                }
            }
        }
    }
}

// ---- k_fill: per-bucket CSR fine fill ---------------------------------------
__global__ __launch_bounds__(256) void k_fill(
    const uint* __restrict__ binned, const int* __restrict__ bcnt,
    int* __restrict__ rowptr, int* __restrict__ csr, int N, int NB)
{
    __shared__ int deg[BSZ];
    __shared__ int cur[BSZ];
    __shared__ int sc[256];
    int b = blockIdx.x, t = threadIdx.x;
    int cv = (t < NB) ? min(bcnt[t], BCAP) : 0;
    sc[t] = cv;
    __syncthreads();
    for (int off = 1; off < 256; off <<= 1) {
        int u = (t >= off) ? sc[t - off] : 0;
        __syncthreads();
        sc[t] += u;
        __syncthreads();
    }
    int total = sc[255];
    int s0 = (b > 0) ? sc[b - 1] : 0;
    int cntb = min(bcnt[b], BCAP);
    __syncthreads();

    int n0 = b << BSH;
    int nn = N - n0; if (nn > BSZ) nn = BSZ;
    deg[t] = 0; deg[t + 256] = 0;
    __syncthreads();
    const uint* bb = binned + (size_t)b * BCAP;
    for (int i = t; i < cntb; i += 256)
        atomicAdd(&deg[bb[i] & (BSZ - 1)], 1);
    __syncthreads();
    int d0 = deg[2 * t], d1 = deg[2 * t + 1];
    int ts = d0 + d1;
    sc[t] = ts;
    __syncthreads();
    for (int off = 1; off < 256; off <<= 1) {
        int u = (t >= off) ? sc[t - off] : 0;
        __syncthreads();
        sc[t] += u;
        __syncthreads();
    }
    int ex = sc[t] - ts + s0;
    if (2 * t < nn)     { rowptr[n0 + 2 * t]     = ex;      cur[2 * t]     = ex; }
    if (2 * t + 1 < nn) { rowptr[n0 + 2 * t + 1] = ex + d0; cur[2 * t + 1] = ex + d0; }
    __syncthreads();
    for (int i = t; i < cntb; i += 256) {
        uint en = bb[i];
        int pos = atomicAdd(&cur[en & (BSZ - 1)], 1);
        csr[pos] = (int)(en >> BSH);
    }
    if (b == 0 && t == 0) rowptr[N] = total;
}

// ---- Layer-1 aggregate + fused bias/ReLU/GEMM2/alpha2 -----------------------
// 32 lanes/node (2 nodes/wave): two 16-lane groups process even/odd edges in
// parallel, merged by shfl_xor(16). Lane sl (0..15) owns 8 fp8 cols of head sl>>3.
__global__ __launch_bounds__(256) void k_aggr1_l2(
    const int* __restrict__ rowptr, const int* __restrict__ csr_src,
    const float* __restrict__ as1, const float* __restrict__ ad1,
    const unsigned char* __restrict__ h1p, const float* __restrict__ b1p,
    const float* __restrict__ W2p, const float* __restrict__ a_src2,
    const float* __restrict__ a_dst2,
    float* __restrict__ h2p, float* __restrict__ as2, float* __restrict__ ad2,
    int N)
{
    int w = threadIdx.x >> 6, l = threadIdx.x & 63;
    int q = l >> 5;                        // node within wave (0/1)
    int u = l & 31;                        // lane within node
    int g = u >> 4;                        // edge group (0/1)
    int sl = u & 15;                       // column lane
    int n = blockIdx.x * 8 + w * 2 + q;
    if (n >= N) return;
    const int h = sl >> 3;                 // this lane's head
    const int boff = sl * 8;               // byte offset within row
    float adv = ad1[n * 2 + h];
    int beg = rowptr[n], end = rowptr[n + 1];
    f32x2 ac01 = {0.f, 0.f}, ac23 = {0.f, 0.f}, ac45 = {0.f, 0.f}, ac67 = {0.f, 0.f};
    float s = 0.f;

    int i = beg;
    for (; i + 8 <= end; i += 8) {         // group g: edges i+g, i+g+2, i+g+4, i+g+6
        int sv[4]; float Av[4]; uint2 Hv[4];
#pragma unroll
        for (int j = 0; j < 4; ++j) sv[j] = csr_src[i + g + 2 * j];
#pragma unroll
        for (int j = 0; j < 4; ++j) Av[j] = as1[sv[j] * 2 + h];
#pragma unroll
        for (int j = 0; j < 4; ++j)
            Hv[j] = *(const uint2*)(h1p + (((size_t)(uint)sv[j]) << 7) + boff);
#pragma unroll
        for (int j = 0; j < 4; ++j) {
            float a = Av[j] + adv; a = a > 0.f ? a : 0.2f * a;
            float e = __expf(a);
            s += e;
            f32x2 ev = {e, e};
            ac01 += ev * __builtin_amdgcn_cvt_pk_f32_fp8((int)Hv[j].x, false);
            ac23 += ev * __builtin_amdgcn_cvt_pk_f32_fp8((int)Hv[j].x, true);
            ac45 += ev * __builtin_amdgcn_cvt_pk_f32_fp8((int)Hv[j].y, false);
            ac67 += ev * __builtin_amdgcn_cvt_pk_f32_fp8((int)Hv[j].y, true);
        }
    }
    for (int k2 = i + g; k2 < end; k2 += 2) {
        int src = csr_src[k2];
        float a = as1[src * 2 + h] + adv; a = a > 0.f ? a : 0.2f * a;
        float e = __expf(a);
        s += e;
        uint2 hv = *(const uint2*)(h1p + (((size_t)(uint)src) << 7) + boff);
        f32x2 ev = {e, e};
        ac01 += ev * __builtin_amdgcn_cvt_pk_f32_fp8((int)hv.x, false);
        ac23 += ev * __builtin_amdgcn_cvt_pk_f32_fp8((int)hv.x, true);
        ac45 += ev * __builtin_amdgcn_cvt_pk_f32_fp8((int)hv.y, false);
        ac67 += ev * __builtin_amdgcn_cvt_pk_f32_fp8((int)hv.y, true);
    }
    // merge edge groups (partner lane = l ^ 16)
    s += __shfl_xor(s, 16, 64);
    ac01[0] += __shfl_xor(ac01[0], 16, 64); ac01[1] += __shfl_xor(ac01[1], 16, 64);
    ac23[0] += __shfl_xor(ac23[0], 16, 64); ac23[1] += __shfl_xor(ac23[1], 16, 64);
    ac45[0] += __shfl_xor(ac45[0], 16, 64); ac45[1] += __shfl_xor(ac45[1], 16, 64);
    ac67[0] += __shfl_xor(ac67[0], 16, 64); ac67[1] += __shfl_xor(ac67[1], 16, 64);

    float inv = 1.f / (s + 1e-16f);

    // fused layer-2 input: v = relu(out1 + b1) in permuted order p = sl*8+j
    float4 bv0 = *(const float4*)&b1p[sl * 8];
    float4 bv1 = *(const float4*)&b1p[sl * 8 + 4];
    float v[8];
    v[0] = fmaxf(ac01[0] * inv + bv0.x, 0.f);
    v[1] = fmaxf(ac01[1] * inv + bv0.y, 0.f);
    v[2] = fmaxf(ac23[0] * inv + bv0.z, 0.f);
    v[3] = fmaxf(ac23[1] * inv + bv0.w, 0.f);
    v[4] = fmaxf(ac45[0] * inv + bv1.x, 0.f);
    v[5] = fmaxf(ac45[1] * inv + bv1.y, 0.f);
    v[6] = fmaxf(ac67[0] * inv + bv1.z, 0.f);
    v[7] = fmaxf(ac67[1] * inv + bv1.w, 0.f);

    // W2p rows sl*8 .. sl*8+7 = 56 contiguous floats
    float w2r[56];
    {
        const float4* wp = (const float4*)(W2p + sl * 56);
#pragma unroll
        for (int k = 0; k < 14; ++k) {
            float4 f = wp[k];
            w2r[4 * k + 0] = f.x; w2r[4 * k + 1] = f.y;
            w2r[4 * k + 2] = f.z; w2r[4 * k + 3] = f.w;
        }
    }
    float p[7];
#pragma unroll
    for (int j = 0; j < 7; ++j) p[j] = 0.f;
#pragma unroll
    for (int r = 0; r < 8; ++r)
#pragma unroll
        for (int j = 0; j < 7; ++j) p[j] += v[r] * w2r[r * 7 + j];
#pragma unroll
    for (int off = 1; off <= 8; off <<= 1)
#pragma unroll
        for (int j = 0; j < 7; ++j) p[j] += __shfl_xor(p[j], off, 64);

    if (u == 0) {
        float asv = 0.f, adv2 = 0.f;
#pragma unroll
        for (int j = 0; j < 7; ++j) {
            h2p[(size_t)n * H2S + j] = p[j];
            asv += p[j] * a_src2[j];
            adv2 += p[j] * a_dst2[j];
        }
        h2p[(size_t)n * H2S + 7] = 0.f;
        as2[n] = asv; ad2[n] = adv2;
    }
}

// ---- Layer-2 aggregate + bias + log_softmax (16 lanes / node) ---------------
// 4 edge slots x 4 col-lanes; slots merged by shfl_xor(4,8).
__global__ __launch_bounds__(256) void k_aggr2ls(
    const int* __restrict__ rowptr, const int* __restrict__ csr_src,
    const float* __restrict__ as2, const float* __restrict__ ad2,
    const float* __restrict__ h2p, const float* __restrict__ b2,
    float* __restrict__ out, int N)
{
    int gt = blockIdx.x * blockDim.x + threadIdx.x;
    int n = gt >> 4, u = gt & 15;
    int es = u >> 2, c = u & 3;          // edge slot, col pair (cols 2c,2c+1)
    if (n >= N) return;
    float adv = ad2[n];
    int beg = rowptr[n], end = rowptr[n + 1];
    f32x2 acc = {0.f, 0.f};
    float s = 0.f;
    int i = beg;
    for (; i + 8 <= end; i += 8) {       // slot es: edges i+es, i+es+4
        int sv[2]; float Av[2]; float2 Hv[2];
        sv[0] = csr_src[i + es];
        sv[1] = csr_src[i + es + 4];
#pragma unroll
        for (int j = 0; j < 2; ++j) Av[j] = as2[sv[j]];
#pragma unroll
        for (int j = 0; j < 2; ++j)
            Hv[j] = *(const float2*)(h2p + ((size_t)(uint)sv[j]) * H2S + 2 * c);
#pragma unroll
        for (int j = 0; j < 2; ++j) {
            float a = Av[j] + adv;
            a = a > 0.f ? a : 0.2f * a;
            float e = __expf(a);
            s += e;
            f32x2 ev = {e, e};
            f32x2 hv = {Hv[j].x, Hv[j].y};
            acc += ev * hv;
        }
    }
    for (int k2 = i + es; k2 < end; k2 += 4) {
        int s0 = csr_src[k2];
        float a = as2[s0] + adv;
        a = a > 0.f ? a : 0.2f * a;
        float e = __expf(a);
        s += e;
        float2 hv2 = *(const float2*)(h2p + ((size_t)(uint)s0) * H2S + 2 * c);
        f32x2 ev = {e, e};
        f32x2 hv = {hv2.x, hv2.y};
        acc += ev * hv;
    }
    // merge the 4 edge slots (stays within the 16-lane node group)
    s += __shfl_xor(s, 4, 64);  s += __shfl_xor(s, 8, 64);
    acc[0] += __shfl_xor(acc[0], 4, 64); acc[0] += __shfl_xor(acc[0], 8, 64);
    acc[1] += __shfl_xor(acc[1], 4, 64); acc[1] += __shfl_xor(acc[1], 8, 64);

    float invs = 1.f / (s + 1e-16f);
    float va = acc[0] * invs + b2[2 * c];
    float vb = (2 * c + 1 < 7) ? acc[1] * invs + b2[2 * c + 1] : -1e30f;
    float m = fmaxf(va, vb);
#pragma unroll
    for (int off = 1; off <= 2; off <<= 1)
        m = fmaxf(m, __shfl_xor(m, off, 4));
    float ex = __expf(va - m) + ((2 * c + 1 < 7) ? __expf(vb - m) : 0.f);
#pragma unroll
    for (int off = 1; off <= 2; off <<= 1)
        ex += __shfl_xor(ex, off, 4);
    float lg = __logf(ex);
    if (es == 0) {
        out[(size_t)n * F_OUT + 2 * c] = va - m - lg;
        if (2 * c + 1 < 7) out[(size_t)n * F_OUT + 2 * c + 1] = vb - m - lg;
    }
}

extern "C" void kernel_launch(void* const* d_in, const int* in_sizes, int n_in,
                              void* d_out, int out_size, void* d_ws, size_t ws_size,
                              hipStream_t stream) {
    const float* x      = (const float*)d_in[0];
    const int*   ei     = (const int*)d_in[1];   // [2,E] int32
    const float* W1     = (const float*)d_in[2];
    const float* a_src1 = (const float*)d_in[3];
    const float* a_dst1 = (const float*)d_in[4];
    const float* b1     = (const float*)d_in[5];
    const float* W2     = (const float*)d_in[6];
    const float* a_src2 = (const float*)d_in[7];
    const float* a_dst2 = (const float*)d_in[8];
    const float* b2     = (const float*)d_in[9];
    float* out = (float*)d_out;

    const int N    = in_sizes[0] / F_IN;
    const int E    = in_sizes[1] / 2;
    const int Etot = E + N;
    const int NB   = (N + BSZ - 1) >> BSH;          // buckets (196 for N=100k)
    const int NBIN = (Etot + BINCH - 1) / BINCH;

    char* ws = (char*)d_ws;
    size_t off = 0;
    auto A = [&](size_t bytes) -> void* {
        char* p = ws + off;
        off += (bytes + 255) & ~(size_t)255;
        return (void*)p;
    };
    ushort* Wsw    = (ushort*)A((size_t)128 * 128 * 2);
    float*  W2p    = (float*) A((size_t)128 * F_OUT * 4);
    float*  b1p    = (float*) A((size_t)128 * 4);
    unsigned char* h1p = (unsigned char*)A((size_t)N * HC);
    float*  as1    = (float*) A((size_t)N * 2 * 4);
    float*  ad1    = (float*) A((size_t)N * 2 * 4);
    int*    rowptr = (int*)   A((size_t)(N + 1) * 4);
    int*    csr    = (int*)   A((size_t)Etot * 4);
    int*    bcnt   = (int*)   A(256 * 4);
    // binned overlays {h2p, as2, ad2}: binned dead after fill phase.
    uint*   binned = (uint*)  A((size_t)NB * BCAP * 4);
    float*  h2p    = (float*)binned;
    float*  as2    = (float*)((char*)binned + (((size_t)N * H2S * 4 + 255) & ~(size_t)255));
    float*  ad2    = (float*)((char*)as2 + (((size_t)N * 4 + 255) & ~(size_t)255));

    hipMemsetAsync(bcnt, 0, 256 * 4, stream);

    k_cvt<<<65, 256, 0, stream>>>(W1, Wsw, W2, b1, W2p, b1p);
    k_bingemm<<<NBIN + (N + 63) / 64, 256, 0, stream>>>(
        ei, E, Etot, NBIN, bcnt, binned,
        x, Wsw, a_src1, a_dst1, h1p, as1, ad1, N);
    k_fill<<<NB, 256, 0, stream>>>(binned, bcnt, rowptr, csr, N, NB);
    k_aggr1_l2<<<(N + 7) / 8, 256, 0, stream>>>(rowptr, csr, as1, ad1, h1p,
                                                b1p, W2p, a_src2, a_dst2,
                                                h2p, as2, ad2, N);
    k_aggr2ls<<<((size_t)N * 16 + 255) / 256, 256, 0, stream>>>(rowptr, csr,
                                                                as2, ad2, h2p, b2, out, N);
}

// Round 14
// 145.498 us; speedup vs baseline: 1.2119x; 1.2119x over previous
//
#include <hip/hip_runtime.h>
#include <hip/hip_bf16.h>

#define F_IN 128
#define HC   128   // H1*C1
#define C1   64
#define F_OUT 7
#define H2S  8      // padded h2 row stride
#define BSH  9      // 512 nodes per bucket
#define BSZ  512
#define BINCH 8192  // edges per WG in binning
#define BCAP 12288  // bucket region capacity (mean ~8700, +~17 sigma)

typedef __attribute__((ext_vector_type(8))) short short8;
typedef __attribute__((ext_vector_type(4))) float f32x4;
typedef __attribute__((ext_vector_type(2))) float f32x2;

__device__ __forceinline__ ushort f2bf(float f) {
    uint u = __builtin_bit_cast(uint, f);
    u = (u + 0x7FFFu + ((u >> 16) & 1u)) >> 16;   // RNE
    return (ushort)u;
}

// fp8-permuted layout: byte b = h*64 + lr*4 + jj  <->  col c = 16*(4*h+jj) + lr
__device__ __forceinline__ int perm_col(int p_byte) {
    int slp = p_byte >> 3, j = p_byte & 7;
    int h = slp >> 3, sg = slp & 7;
    int lr = 2 * sg + (j >> 2), jj = j & 3;
    return 16 * (4 * h + jj) + lr;
}

// ---- k_cvt: blocks [0,64) W1 -> bf16 transposed+swizzled; [64] W2p/b1p+bcnt -
__global__ __launch_bounds__(256) void k_cvt(
    const float* __restrict__ W1, ushort* __restrict__ Wsw,
    const float* __restrict__ W2, const float* __restrict__ b1,
    float* __restrict__ W2p, float* __restrict__ b1p, int* __restrict__ bcnt)
{
    int b = blockIdx.x, t = threadIdx.x;
    if (b < 64) {
        int i = b * 256 + t;                // 0..16383
        int k = i >> 7, n = i & 127;
        float v = W1[k * HC + n];
        int idx = n * 128 + (((k & ~7) ^ ((n & 7) << 3)) | (k & 7));
        Wsw[idx] = f2bf(v);
    } else {
        bcnt[t] = 0;
        for (int i = t; i < 128 * F_OUT; i += 256) {
            int p = i / F_OUT, o = i - p * F_OUT;
            W2p[i] = W2[perm_col(p) * F_OUT + o];
        }
        if (t < 128) b1p[t] = b1[perm_col(t)];
    }
}

// ---- k_bingemm: blocks [0,NBIN) edge binning; [NBIN,...) GEMM1 MFMA ---------
__global__ __launch_bounds__(256) void k_bingemm(
    const int* __restrict__ ei, int E, int Etot, int NBIN,
    int* __restrict__ bcnt, uint* __restrict__ binned,
    const float* __restrict__ x, const ushort* __restrict__ Wsw,
    const float* __restrict__ a_src, const float* __restrict__ a_dst,
    unsigned char* __restrict__ h1p, float* __restrict__ as1, float* __restrict__ ad1,
    int N)
{
    __shared__ __align__(16) char smem[128 * 128 * 2];
    const int t = threadIdx.x;

    if ((int)blockIdx.x < NBIN) {
        // ---------------- edge binning (single pass, fixed-capacity) --------
        int* hist = (int*)smem;          // [256]
        int* base = hist + 256;          // [256]
        hist[t] = 0;
        __syncthreads();
        long c0 = (long)blockIdx.x * BINCH;
#pragma unroll
        for (int i = 0; i < BINCH / 256; ++i) {
            long e = c0 + t + i * 256;
            if (e < Etot) {
                int d = (e < E) ? ei[E + e] : (int)(e - E);
                atomicAdd(&hist[d >> BSH], 1);
            }
        }
        __syncthreads();
        base[t] = t * BCAP + ((hist[t] > 0) ? atomicAdd(&bcnt[t], hist[t]) : 0);
        __syncthreads();
#pragma unroll
        for (int i = 0; i < BINCH / 256; ++i) {
            long e = c0 + t + i * 256;
            if (e < Etot) {
                int s, d;
                if (e < E) { s = ei[e]; d = ei[E + e]; } else { s = (int)(e - E); d = s; }
                int bkt = d >> BSH;
                int pos = atomicAdd(&base[bkt], 1);
                if (pos < (bkt + 1) * BCAP)   // overflow guard (never for this data)
                    binned[pos] = ((uint)s << BSH) | (uint)(d & (BSZ - 1));
            }
        }
    } else {
        // ---------------- GEMM1 (bf16 MFMA, fused alphas, fp8 h1 out) -------
        ushort* Bs = (ushort*)smem;     // pre-swizzled [n][k] bf16
        const int w = t >> 6, l = t & 63;
        const int lr = l & 15, hi = l >> 4;
        const int n0 = (blockIdx.x - NBIN) * 64;

        {
            const uint4* src = (const uint4*)Wsw;
            uint4* dst = (uint4*)Bs;
#pragma unroll
            for (int it = 0; it < 8; ++it) dst[t + it * 256] = src[t + it * 256];
        }
        __syncthreads();

        f32x4 acc[8];
#pragma unroll
        for (int j = 0; j < 8; ++j) acc[j] = (f32x4){0.f, 0.f, 0.f, 0.f};

        int arow = n0 + w * 16 + lr;
        if (arow >= N) arow = N - 1;
        const float* aptr = x + (size_t)arow * F_IN + hi * 8;

#pragma unroll
        for (int kt = 0; kt < 4; ++kt) {
            float4 f0 = *(const float4*)(aptr + kt * 32);
            float4 f1 = *(const float4*)(aptr + kt * 32 + 4);
            short8 a;
            a[0] = (short)f2bf(f0.x); a[1] = (short)f2bf(f0.y);
            a[2] = (short)f2bf(f0.z); a[3] = (short)f2bf(f0.w);
            a[4] = (short)f2bf(f1.x); a[5] = (short)f2bf(f1.y);
            a[6] = (short)f2bf(f1.z); a[7] = (short)f2bf(f1.w);
#pragma unroll
            for (int j = 0; j < 8; ++j) {
                int rn = 16 * j + lr;
                int kidx = (kt * 32 + hi * 8) ^ ((rn & 7) << 3);
                short8 b = *(const short8*)(Bs + rn * 128 + kidx);
                acc[j] = __builtin_amdgcn_mfma_f32_16x16x32_bf16(a, b, acc[j], 0, 0, 0);
            }
        }

        float as_[8], ad_[8];
#pragma unroll
        for (int j = 0; j < 8; ++j) {
            int hd = j >> 2;
            int c = 16 * (j & 3) + lr;
            as_[j] = a_src[hd * C1 + c];
            ad_[j] = a_dst[hd * C1 + c];
        }
#pragma unroll
        for (int i = 0; i < 4; ++i) {
            int r = n0 + w * 16 + hi * 4 + i;
            float ps0 = 0, ps1 = 0, pd0 = 0, pd1 = 0;
#pragma unroll
            for (int j = 0; j < 4; ++j) { ps0 += acc[j][i] * as_[j]; pd0 += acc[j][i] * ad_[j]; }
#pragma unroll
            for (int j = 4; j < 8; ++j) { ps1 += acc[j][i] * as_[j]; pd1 += acc[j][i] * ad_[j]; }
#pragma unroll
            for (int off = 1; off <= 8; off <<= 1) {
                ps0 += __shfl_xor(ps0, off, 64);
                ps1 += __shfl_xor(ps1, off, 64);
                pd0 += __shfl_xor(pd0, off, 64);
                pd1 += __shfl_xor(pd1, off, 64);
            }
            if (r < N) {
                // head-split fp8 layout: head0 word at byte lr*4, head1 at 64+lr*4
                int w0 = 0, w1 = 0;
                w0 = __builtin_amdgcn_cvt_pk_fp8_f32(acc[0][i], acc[1][i], w0, false);
                w0 = __builtin_amdgcn_cvt_pk_fp8_f32(acc[2][i], acc[3][i], w0, true);
                w1 = __builtin_amdgcn_cvt_pk_fp8_f32(acc[4][i], acc[5][i], w1, false);
                w1 = __builtin_amdgcn_cvt_pk_fp8_f32(acc[6][i], acc[7][i], w1, true);
                *(uint*)(h1p + (size_t)r * HC + lr * 4)      = (uint)w0;
                *(uint*)(h1p + (size_t)r * HC + 64 + lr * 4) = (uint)w1;
                if (lr == 0) {
                    as1[r * 2 + 0] = ps0; as1[r * 2 + 1] = ps1;
                    ad1[r * 2 + 0] = pd0; ad1[r * 2 + 1] = pd1;
                }
            }
        }
    }
}

// ---- k_fill: per-bucket CSR fine fill ---------------------------------------
__global__ __launch_bounds__(256) void k_fill(
    const uint* __restrict__ binned, const int* __restrict__ bcnt,
    int* __restrict__ rowptr, int* __restrict__ csr, int N, int NB)
{
    __shared__ int deg[BSZ];
    __shared__ int cur[BSZ];
    __shared__ int sc[256];
    int b = blockIdx.x, t = threadIdx.x;
    int cv = (t < NB) ? min(bcnt[t], BCAP) : 0;
    sc[t] = cv;
    __syncthreads();
    for (int off = 1; off < 256; off <<= 1) {
        int u = (t >= off) ? sc[t - off] : 0;
        __syncthreads();
        sc[t] += u;
        __syncthreads();
    }
    int total = sc[255];
    int s0 = (b > 0) ? sc[b - 1] : 0;
    int cntb = min(bcnt[b], BCAP);
    __syncthreads();

    int n0 = b << BSH;
    int nn = N - n0; if (nn > BSZ) nn = BSZ;
    deg[t] = 0; deg[t + 256] = 0;
    __syncthreads();
    const uint* bb = binned + (size_t)b * BCAP;
    for (int i = t; i < cntb; i += 256)
        atomicAdd(&deg[bb[i] & (BSZ - 1)], 1);
    __syncthreads();
    int d0 = deg[2 * t], d1 = deg[2 * t + 1];
    int ts = d0 + d1;
    sc[t] = ts;
    __syncthreads();
    for (int off = 1; off < 256; off <<= 1) {
        int u = (t >= off) ? sc[t - off] : 0;
        __syncthreads();
        sc[t] += u;
        __syncthreads();
    }
    int ex = sc[t] - ts + s0;
    if (2 * t < nn)     { rowptr[n0 + 2 * t]     = ex;      cur[2 * t]     = ex; }
    if (2 * t + 1 < nn) { rowptr[n0 + 2 * t + 1] = ex + d0; cur[2 * t + 1] = ex + d0; }
    __syncthreads();
    for (int i = t; i < cntb; i += 256) {
        uint en = bb[i];
        int pos = atomicAdd(&cur[en & (BSZ - 1)], 1);
        csr[pos] = (int)(en >> BSH);
    }
    if (b == 0 && t == 0) rowptr[N] = total;
}

// ---- Layer-1 aggregate (fp8, head-split) + fused bias/ReLU/GEMM2/alpha2 -----
// 16 lanes per node (natural order); lane sl: head h=sl>>3. Unroll 8 for MLP.
__global__ __launch_bounds__(256) void k_aggr1_l2(
    const int* __restrict__ rowptr, const int* __restrict__ csr_src,
    const float* __restrict__ as1, const float* __restrict__ ad1,
    const unsigned char* __restrict__ h1p, const float* __restrict__ b1p,
    const float* __restrict__ W2p, const float* __restrict__ a_src2,
    const float* __restrict__ a_dst2,
    float* __restrict__ h2p, float* __restrict__ as2, float* __restrict__ ad2,
    int N)
{
    int w = threadIdx.x >> 6, l = threadIdx.x & 63;
    int q = l >> 4, sl = l & 15;
    int n = blockIdx.x * 16 + w * 4 + q;
    if (n >= N) return;
    const int h = sl >> 3;                 // this lane's head
    const int boff = sl * 8;               // byte offset within row
    float adv = ad1[n * 2 + h];
    int beg = rowptr[n], end = rowptr[n + 1];
    f32x2 ac01 = {0.f, 0.f}, ac23 = {0.f, 0.f}, ac45 = {0.f, 0.f}, ac67 = {0.f, 0.f};
    float s = 0.f;

    int i = beg;
    for (; i + 8 <= end; i += 8) {
        int sv[8]; float Av[8]; uint2 Hv[8];
#pragma unroll
        for (int j = 0; j < 8; ++j) sv[j] = csr_src[i + j];
#pragma unroll
        for (int j = 0; j < 8; ++j) Av[j] = as1[sv[j] * 2 + h];
#pragma unroll
        for (int j = 0; j < 8; ++j)
            Hv[j] = *(const uint2*)(h1p + (((size_t)(uint)sv[j]) << 7) + boff);
#pragma unroll
        for (int j = 0; j < 8; ++j) {
            float a = Av[j] + adv; a = a > 0.f ? a : 0.2f * a;
            float e = __expf(a);
            s += e;
            f32x2 ev = {e, e};
            ac01 += ev * __builtin_amdgcn_cvt_pk_f32_fp8((int)Hv[j].x, false);
            ac23 += ev * __builtin_amdgcn_cvt_pk_f32_fp8((int)Hv[j].x, true);
            ac45 += ev * __builtin_amdgcn_cvt_pk_f32_fp8((int)Hv[j].y, false);
            ac67 += ev * __builtin_amdgcn_cvt_pk_f32_fp8((int)Hv[j].y, true);
        }
    }
    for (; i + 4 <= end; i += 4) {
        int sv[4]; float Av[4]; uint2 Hv[4];
#pragma unroll
        for (int j = 0; j < 4; ++j) sv[j] = csr_src[i + j];
#pragma unroll
        for (int j = 0; j < 4; ++j) Av[j] = as1[sv[j] * 2 + h];
#pragma unroll
        for (int j = 0; j < 4; ++j)
            Hv[j] = *(const uint2*)(h1p + (((size_t)(uint)sv[j]) << 7) + boff);
#pragma unroll
        for (int j = 0; j < 4; ++j) {
            float a = Av[j] + adv; a = a > 0.f ? a : 0.2f * a;
            float e = __expf(a);
            s += e;
            f32x2 ev = {e, e};
            ac01 += ev * __builtin_amdgcn_cvt_pk_f32_fp8((int)Hv[j].x, false);
            ac23 += ev * __builtin_amdgcn_cvt_pk_f32_fp8((int)Hv[j].x, true);
            ac45 += ev * __builtin_amdgcn_cvt_pk_f32_fp8((int)Hv[j].y, false);
            ac67 += ev * __builtin_amdgcn_cvt_pk_f32_fp8((int)Hv[j].y, true);
        }
    }
    for (; i < end; ++i) {
        int src = csr_src[i];
        float a = as1[src * 2 + h] + adv; a = a > 0.f ? a : 0.2f * a;
        float e = __expf(a);
        s += e;
        uint2 hv = *(const uint2*)(h1p + (((size_t)(uint)src) << 7) + boff);
        f32x2 ev = {e, e};
        ac01 += ev * __builtin_amdgcn_cvt_pk_f32_fp8((int)hv.x, false);
        ac23 += ev * __builtin_amdgcn_cvt_pk_f32_fp8((int)hv.x, true);
        ac45 += ev * __builtin_amdgcn_cvt_pk_f32_fp8((int)hv.y, false);
        ac67 += ev * __builtin_amdgcn_cvt_pk_f32_fp8((int)hv.y, true);
    }
    float inv = 1.f / (s + 1e-16f);

    // fused layer-2 input: v = relu(out1 + b1) in permuted order p = sl*8+j
    float4 bv0 = *(const float4*)&b1p[sl * 8];
    float4 bv1 = *(const float4*)&b1p[sl * 8 + 4];
    float v[8];
    v[0] = fmaxf(ac01[0] * inv + bv0.x, 0.f);
    v[1] = fmaxf(ac01[1] * inv + bv0.y, 0.f);
    v[2] = fmaxf(ac23[0] * inv + bv0.z, 0.f);
    v[3] = fmaxf(ac23[1] * inv + bv0.w, 0.f);
    v[4] = fmaxf(ac45[0] * inv + bv1.x, 0.f);
    v[5] = fmaxf(ac45[1] * inv + bv1.y, 0.f);
    v[6] = fmaxf(ac67[0] * inv + bv1.z, 0.f);
    v[7] = fmaxf(ac67[1] * inv + bv1.w, 0.f);

    // W2p rows sl*8 .. sl*8+7 = 56 contiguous floats
    float w2r[56];
    {
        const float4* wp = (const float4*)(W2p + sl * 56);
#pragma unroll
        for (int k = 0; k < 14; ++k) {
            float4 f = wp[k];
            w2r[4 * k + 0] = f.x; w2r[4 * k + 1] = f.y;
            w2r[4 * k + 2] = f.z; w2r[4 * k + 3] = f.w;
        }
    }
    float p[7];
#pragma unroll
    for (int j = 0; j < 7; ++j) p[j] = 0.f;
#pragma unroll
    for (int r = 0; r < 8; ++r)
#pragma unroll
        for (int j = 0; j < 7; ++j) p[j] += v[r] * w2r[r * 7 + j];
#pragma unroll
    for (int off = 1; off <= 8; off <<= 1)
#pragma unroll
        for (int j = 0; j < 7; ++j) p[j] += __shfl_xor(p[j], off, 64);

    if (sl == 0) {
        float asv = 0.f, adv2 = 0.f;
#pragma unroll
        for (int j = 0; j < 7; ++j) {
            h2p[(size_t)n * H2S + j] = p[j];
            asv += p[j] * a_src2[j];
            adv2 += p[j] * a_dst2[j];
        }
        h2p[(size_t)n * H2S + 7] = 0.f;
        as2[n] = asv; ad2[n] = adv2;
    }
}

// ---- Layer-2 aggregate + bias + log_softmax fused (4 lanes / node) ----------
__global__ __launch_bounds__(256) void k_aggr2ls(
    const int* __restrict__ rowptr, const int* __restrict__ csr_src,
    const float* __restrict__ as2, const float* __restrict__ ad2,
    const float* __restrict__ h2p, const float* __restrict__ b2,
    float* __restrict__ out, int N)
{
    int g = blockIdx.x * blockDim.x + threadIdx.x;
    int n = g >> 2, l = g & 3;          // lane handles cols 2l, 2l+1 (col7=pad)
    if (n >= N) return;
    float adv = ad2[n];
    int beg = rowptr[n], end = rowptr[n + 1];
    f32x2 acc = {0.f, 0.f};
    float s = 0.f;
    int i = beg;
    for (; i + 4 <= end; i += 4) {
        int sv[4]; float Av[4]; float2 Hv[4];
#pragma unroll
        for (int j = 0; j < 4; ++j) sv[j] = csr_src[i + j];
#pragma unroll
        for (int j = 0; j < 4; ++j) Av[j] = as2[sv[j]];
#pragma unroll
        for (int j = 0; j < 4; ++j)
            Hv[j] = *(const float2*)(h2p + ((size_t)(uint)sv[j]) * H2S + 2 * l);
#pragma unroll
        for (int j = 0; j < 4; ++j) {
            float a = Av[j] + adv;
            a = a > 0.f ? a : 0.2f * a;
            float e = __expf(a);
            s += e;
            f32x2 ev = {e, e};
            f32x2 hv = {Hv[j].x, Hv[j].y};
            acc += ev * hv;
        }
    }
    for (; i < end; ++i) {
        int s0 = csr_src[i];
        float a = as2[s0] + adv;
        a = a > 0.f ? a : 0.2f * a;
        float e = __expf(a);
        s += e;
        float2 hv2 = *(const float2*)(h2p + ((size_t)(uint)s0) * H2S + 2 * l);
        f32x2 ev = {e, e};
        f32x2 hv = {hv2.x, hv2.y};
        acc += ev * hv;
    }
    float invs = 1.f / (s + 1e-16f);
    float va = acc[0] * invs + b2[2 * l];
    float vb = (2 * l + 1 < 7) ? acc[1] * invs + b2[2 * l + 1] : -1e30f;
    float m = fmaxf(va, vb);
#pragma unroll
    for (int off = 1; off <= 2; off <<= 1)
        m = fmaxf(m, __shfl_xor(m, off, 4));
    float ex = __expf(va - m) + ((2 * l + 1 < 7) ? __expf(vb - m) : 0.f);
#pragma unroll
    for (int off = 1; off <= 2; off <<= 1)
        ex += __shfl_xor(ex, off, 4);
    float lg = __logf(ex);
    out[(size_t)n * F_OUT + 2 * l] = va - m - lg;
    if (2 * l + 1 < 7) out[(size_t)n * F_OUT + 2 * l + 1] = vb - m - lg;
}

extern "C" void kernel_launch(void* const* d_in, const int* in_sizes, int n_in,
                              void* d_out, int out_size, void* d_ws, size_t ws_size,
                              hipStream_t stream) {
    const float* x      = (const float*)d_in[0];
    const int*   ei     = (const int*)d_in[1];   // [2,E] int32
    const float* W1     = (const float*)d_in[2];
    const float* a_src1 = (const float*)d_in[3];
    const float* a_dst1 = (const float*)d_in[4];
    const float* b1     = (const float*)d_in[5];
    const float* W2     = (const float*)d_in[6];
    const float* a_src2 = (const float*)d_in[7];
    const float* a_dst2 = (const float*)d_in[8];
    const float* b2     = (const float*)d_in[9];
    float* out = (float*)d_out;

    const int N    = in_sizes[0] / F_IN;
    const int E    = in_sizes[1] / 2;
    const int Etot = E + N;
    const int NB   = (N + BSZ - 1) >> BSH;          // buckets (196 for N=100k)
    const int NBIN = (Etot + BINCH - 1) / BINCH;

    char* ws = (char*)d_ws;
    size_t off = 0;
    auto A = [&](size_t bytes) -> void* {
        char* p = ws + off;
        off += (bytes + 255) & ~(size_t)255;
        return (void*)p;
    };
    ushort* Wsw    = (ushort*)A((size_t)128 * 128 * 2);
    float*  W2p    = (float*) A((size_t)128 * F_OUT * 4);
    float*  b1p    = (float*) A((size_t)128 * 4);
    unsigned char* h1p = (unsigned char*)A((size_t)N * HC);
    float*  as1    = (float*) A((size_t)N * 2 * 4);
    float*  ad1    = (float*) A((size_t)N * 2 * 4);
    int*    rowptr = (int*)   A((size_t)(N + 1) * 4);
    int*    csr    = (int*)   A((size_t)Etot * 4);
    int*    bcnt   = (int*)   A(256 * 4);
    // binned overlays {h2p, as2, ad2}: binned dead after fill phase.
    uint*   binned = (uint*)  A((size_t)NB * BCAP * 4);
    float*  h2p    = (float*)binned;
    float*  as2    = (float*)((char*)binned + (((size_t)N * H2S * 4 + 255) & ~(size_t)255));
    float*  ad2    = (float*)((char*)as2 + (((size_t)N * 4 + 255) & ~(size_t)255));

    k_cvt<<<65, 256, 0, stream>>>(W1, Wsw, W2, b1, W2p, b1p, bcnt);
    k_bingemm<<<NBIN + (N + 63) / 64, 256, 0, stream>>>(
        ei, E, Etot, NBIN, bcnt, binned,
        x, Wsw, a_src1, a_dst1, h1p, as1, ad1, N);
    k_fill<<<NB, 256, 0, stream>>>(binned, bcnt, rowptr, csr, N, NB);
    k_aggr1_l2<<<(N + 15) / 16, 256, 0, stream>>>(rowptr, csr, as1, ad1, h1p,
                                                  b1p, W2p, a_src2, a_dst2,
                                                  h2p, as2, ad2, N);
    k_aggr2ls<<<((size_t)N * 4 + 255) / 256, 256, 0, stream>>>(rowptr, csr,
                                                               as2, ad2, h2p, b2, out, N);
}

// Round 15
// 145.493 us; speedup vs baseline: 1.2119x; 1.0000x over previous
//
#include <hip/hip_runtime.h>
#include <hip/hip_bf16.h>

#define F_IN 128
#define HC   128   // H1*C1
#define C1   64
#define F_OUT 7
#define H2S  8      // padded h2 row stride
#define BSH  9      // 512 nodes per bucket
#define BSZ  512
#define BINCH 8192  // edges per WG in binning
#define BCAP 12288  // bucket region capacity (mean ~8700, +~17 sigma)
#define NXCD 8

typedef __attribute__((ext_vector_type(8))) short short8;
typedef __attribute__((ext_vector_type(4))) float f32x4;
typedef __attribute__((ext_vector_type(2))) float f32x2;

__device__ __forceinline__ ushort f2bf(float f) {
    uint u = __builtin_bit_cast(uint, f);
    u = (u + 0x7FFFu + ((u >> 16) & 1u)) >> 16;   // RNE
    return (ushort)u;
}

// fp8-permuted layout: byte b = h*64 + lr*4 + jj  <->  col c = 16*(4*h+jj) + lr
__device__ __forceinline__ int perm_col(int p_byte) {
    int slp = p_byte >> 3, j = p_byte & 7;
    int h = slp >> 3, sg = slp & 7;
    int lr = 2 * sg + (j >> 2), jj = j & 3;
    return 16 * (4 * h + jj) + lr;
}

// bijective XCD-contiguous block swizzle (m204): HW round-robins blockIdx%8
// across XCDs; remap so each XCD owns a CONTIGUOUS logical block range
// (neighboring blocks share bucket-local csr/rowptr -> per-XCD L2 locality).
__device__ __forceinline__ int xcd_swz(int bid, int nwg) {
    int q = nwg / NXCD, r = nwg % NXCD;
    int xcd = bid % NXCD, pos = bid / NXCD;
    return (xcd < r) ? xcd * (q + 1) + pos
                     : r * (q + 1) + (xcd - r) * q + pos;
}

// ---- k_cvt: blocks [0,64) W1 -> bf16 transposed+swizzled; [64] W2p/b1p+bcnt -
__global__ __launch_bounds__(256) void k_cvt(
    const float* __restrict__ W1, ushort* __restrict__ Wsw,
    const float* __restrict__ W2, const float* __restrict__ b1,
    float* __restrict__ W2p, float* __restrict__ b1p, int* __restrict__ bcnt)
{
    int b = blockIdx.x, t = threadIdx.x;
    if (b < 64) {
        int i = b * 256 + t;                // 0..16383
        int k = i >> 7, n = i & 127;
        float v = W1[k * HC + n];
        int idx = n * 128 + (((k & ~7) ^ ((n & 7) << 3)) | (k & 7));
        Wsw[idx] = f2bf(v);
    } else {
        bcnt[t] = 0;
        for (int i = t; i < 128 * F_OUT; i += 256) {
            int p = i / F_OUT, o = i - p * F_OUT;
            W2p[i] = W2[perm_col(p) * F_OUT + o];
        }
        if (t < 128) b1p[t] = b1[perm_col(t)];
    }
}

// ---- k_bingemm: blocks [0,NBIN) edge binning; [NBIN,...) GEMM1 MFMA ---------
__global__ __launch_bounds__(256) void k_bingemm(
    const int* __restrict__ ei, int E, int Etot, int NBIN,
    int* __restrict__ bcnt, uint* __restrict__ binned,
    const float* __restrict__ x, const ushort* __restrict__ Wsw,
    const float* __restrict__ a_src, const float* __restrict__ a_dst,
    unsigned char* __restrict__ h1p, float* __restrict__ as1, float* __restrict__ ad1,
    int N)
{
    __shared__ __align__(16) char smem[128 * 128 * 2];
    const int t = threadIdx.x;

    if ((int)blockIdx.x < NBIN) {
        // ---------------- edge binning (single pass, fixed-capacity) --------
        int* hist = (int*)smem;          // [256]
        int* base = hist + 256;          // [256]
        hist[t] = 0;
        __syncthreads();
        long c0 = (long)blockIdx.x * BINCH;
#pragma unroll
        for (int i = 0; i < BINCH / 256; ++i) {
            long e = c0 + t + i * 256;
            if (e < Etot) {
                int d = (e < E) ? ei[E + e] : (int)(e - E);
                atomicAdd(&hist[d >> BSH], 1);
            }
        }
        __syncthreads();
        base[t] = t * BCAP + ((hist[t] > 0) ? atomicAdd(&bcnt[t], hist[t]) : 0);
        __syncthreads();
#pragma unroll
        for (int i = 0; i < BINCH / 256; ++i) {
            long e = c0 + t + i * 256;
            if (e < Etot) {
                int s, d;
                if (e < E) { s = ei[e]; d = ei[E + e]; } else { s = (int)(e - E); d = s; }
                int bkt = d >> BSH;
                int pos = atomicAdd(&base[bkt], 1);
                if (pos < (bkt + 1) * BCAP)   // overflow guard (never for this data)
                    binned[pos] = ((uint)s << BSH) | (uint)(d & (BSZ - 1));
            }
        }
    } else {
        // ---------------- GEMM1 (bf16 MFMA, fused alphas, fp8 h1 out) -------
        ushort* Bs = (ushort*)smem;     // pre-swizzled [n][k] bf16
        const int w = t >> 6, l = t & 63;
        const int lr = l & 15, hi = l >> 4;
        const int n0 = (blockIdx.x - NBIN) * 64;

        {
            const uint4* src = (const uint4*)Wsw;
            uint4* dst = (uint4*)Bs;
#pragma unroll
            for (int it = 0; it < 8; ++it) dst[t + it * 256] = src[t + it * 256];
        }
        __syncthreads();

        f32x4 acc[8];
#pragma unroll
        for (int j = 0; j < 8; ++j) acc[j] = (f32x4){0.f, 0.f, 0.f, 0.f};

        int arow = n0 + w * 16 + lr;
        if (arow >= N) arow = N - 1;
        const float* aptr = x + (size_t)arow * F_IN + hi * 8;

#pragma unroll
        for (int kt = 0; kt < 4; ++kt) {
            float4 f0 = *(const float4*)(aptr + kt * 32);
            float4 f1 = *(const float4*)(aptr + kt * 32 + 4);
            short8 a;
            a[0] = (short)f2bf(f0.x); a[1] = (short)f2bf(f0.y);
            a[2] = (short)f2bf(f0.z); a[3] = (short)f2bf(f0.w);
            a[4] = (short)f2bf(f1.x); a[5] = (short)f2bf(f1.y);
            a[6] = (short)f2bf(f1.z); a[7] = (short)f2bf(f1.w);
#pragma unroll
            for (int j = 0; j < 8; ++j) {
                int rn = 16 * j + lr;
                int kidx = (kt * 32 + hi * 8) ^ ((rn & 7) << 3);
                short8 b = *(const short8*)(Bs + rn * 128 + kidx);
                acc[j] = __builtin_amdgcn_mfma_f32_16x16x32_bf16(a, b, acc[j], 0, 0, 0);
            }
        }

        float as_[8], ad_[8];
#pragma unroll
        for (int j = 0; j < 8; ++j) {
            int hd = j >> 2;
            int c = 16 * (j & 3) + lr;
            as_[j] = a_src[hd * C1 + c];
            ad_[j] = a_dst[hd * C1 + c];
        }
#pragma unroll
        for (int i = 0; i < 4; ++i) {
            int r = n0 + w * 16 + hi * 4 + i;
            float ps0 = 0, ps1 = 0, pd0 = 0, pd1 = 0;
#pragma unroll
            for (int j = 0; j < 4; ++j) { ps0 += acc[j][i] * as_[j]; pd0 += acc[j][i] * ad_[j]; }
#pragma unroll
            for (int j = 4; j < 8; ++j) { ps1 += acc[j][i] * as_[j]; pd1 += acc[j][i] * ad_[j]; }
#pragma unroll
            for (int off = 1; off <= 8; off <<= 1) {
                ps0 += __shfl_xor(ps0, off, 64);
                ps1 += __shfl_xor(ps1, off, 64);
                pd0 += __shfl_xor(pd0, off, 64);
                pd1 += __shfl_xor(pd1, off, 64);
            }
            if (r < N) {
                // head-split fp8 layout: head0 word at byte lr*4, head1 at 64+lr*4
                int w0 = 0, w1 = 0;
                w0 = __builtin_amdgcn_cvt_pk_fp8_f32(acc[0][i], acc[1][i], w0, false);
                w0 = __builtin_amdgcn_cvt_pk_fp8_f32(acc[2][i], acc[3][i], w0, true);
                w1 = __builtin_amdgcn_cvt_pk_fp8_f32(acc[4][i], acc[5][i], w1, false);
                w1 = __builtin_amdgcn_cvt_pk_fp8_f32(acc[6][i], acc[7][i], w1, true);
                *(uint*)(h1p + (size_t)r * HC + lr * 4)      = (uint)w0;
                *(uint*)(h1p + (size_t)r * HC + 64 + lr * 4) = (uint)w1;
                if (lr == 0) {
                    as1[r * 2 + 0] = ps0; as1[r * 2 + 1] = ps1;
                    ad1[r * 2 + 0] = pd0; ad1[r * 2 + 1] = pd1;
                }
            }
        }
    }
}

// ---- k_fill: per-bucket CSR fine fill ---------------------------------------
__global__ __launch_bounds__(256) void k_fill(
    const uint* __restrict__ binned, const int* __restrict__ bcnt,
    int* __restrict__ rowptr, int* __restrict__ csr, int N, int NB)
{
    __shared__ int deg[BSZ];
    __shared__ int cur[BSZ];
    __shared__ int sc[256];
    int b = blockIdx.x, t = threadIdx.x;
    int cv = (t < NB) ? min(bcnt[t], BCAP) : 0;
    sc[t] = cv;
    __syncthreads();
    for (int off = 1; off < 256; off <<= 1) {
        int u = (t >= off) ? sc[t - off] : 0;
        __syncthreads();
        sc[t] += u;
        __syncthreads();
    }
    int total = sc[255];
    int s0 = (b > 0) ? sc[b - 1] : 0;
    int cntb = min(bcnt[b], BCAP);
    __syncthreads();

    int n0 = b << BSH;
    int nn = N - n0; if (nn > BSZ) nn = BSZ;
    deg[t] = 0; deg[t + 256] = 0;
    __syncthreads();
    const uint* bb = binned + (size_t)b * BCAP;
    for (int i = t; i < cntb; i += 256)
        atomicAdd(&deg[bb[i] & (BSZ - 1)], 1);
    __syncthreads();
    int d0 = deg[2 * t], d1 = deg[2 * t + 1];
    int ts = d0 + d1;
    sc[t] = ts;
    __syncthreads();
    for (int off = 1; off < 256; off <<= 1) {
        int u = (t >= off) ? sc[t - off] : 0;
        __syncthreads();
        sc[t] += u;
        __syncthreads();
    }
    int ex = sc[t] - ts + s0;
    if (2 * t < nn)     { rowptr[n0 + 2 * t]     = ex;      cur[2 * t]     = ex; }
    if (2 * t + 1 < nn) { rowptr[n0 + 2 * t + 1] = ex + d0; cur[2 * t + 1] = ex + d0; }
    __syncthreads();
    for (int i = t; i < cntb; i += 256) {
        uint en = bb[i];
        int pos = atomicAdd(&cur[en & (BSZ - 1)], 1);
        csr[pos] = (int)(en >> BSH);
    }
    if (b == 0 && t == 0) rowptr[N] = total;
}

// ---- Layer-1 aggregate (fp8, head-split) + fused bias/ReLU/GEMM2/alpha2 -----
// 16 lanes per node, natural node order, XCD-contiguous block swizzle.
__global__ __launch_bounds__(256) void k_aggr1_l2(
    const int* __restrict__ rowptr, const int* __restrict__ csr_src,
    const float* __restrict__ as1, const float* __restrict__ ad1,
    const unsigned char* __restrict__ h1p, const float* __restrict__ b1p,
    const float* __restrict__ W2p, const float* __restrict__ a_src2,
    const float* __restrict__ a_dst2,
    float* __restrict__ h2p, float* __restrict__ as2, float* __restrict__ ad2,
    int N)
{
    int bid = xcd_swz(blockIdx.x, gridDim.x);
    int w = threadIdx.x >> 6, l = threadIdx.x & 63;
    int q = l >> 4, sl = l & 15;
    int n = bid * 16 + w * 4 + q;
    if (n >= N) return;
    const int h = sl >> 3;                 // this lane's head
    const int boff = sl * 8;               // byte offset within row
    float adv = ad1[n * 2 + h];
    int beg = rowptr[n], end = rowptr[n + 1];
    f32x2 ac01 = {0.f, 0.f}, ac23 = {0.f, 0.f}, ac45 = {0.f, 0.f}, ac67 = {0.f, 0.f};
    float s = 0.f;

    int i = beg;
    for (; i + 8 <= end; i += 8) {
        int sv[8]; float Av[8]; uint2 Hv[8];
#pragma unroll
        for (int j = 0; j < 8; ++j) sv[j] = csr_src[i + j];
#pragma unroll
        for (int j = 0; j < 8; ++j) Av[j] = as1[sv[j] * 2 + h];
#pragma unroll
        for (int j = 0; j < 8; ++j)
            Hv[j] = *(const uint2*)(h1p + (((size_t)(uint)sv[j]) << 7) + boff);
#pragma unroll
        for (int j = 0; j < 8; ++j) {
            float a = Av[j] + adv; a = a > 0.f ? a : 0.2f * a;
            float e = __expf(a);
            s += e;
            f32x2 ev = {e, e};
            ac01 += ev * __builtin_amdgcn_cvt_pk_f32_fp8((int)Hv[j].x, false);
            ac23 += ev * __builtin_amdgcn_cvt_pk_f32_fp8((int)Hv[j].x, true);
            ac45 += ev * __builtin_amdgcn_cvt_pk_f32_fp8((int)Hv[j].y, false);
            ac67 += ev * __builtin_amdgcn_cvt_pk_f32_fp8((int)Hv[j].y, true);
        }
    }
    for (; i + 4 <= end; i += 4) {
        int sv[4]; float Av[4]; uint2 Hv[4];
#pragma unroll
        for (int j = 0; j < 4; ++j) sv[j] = csr_src[i + j];
#pragma unroll
        for (int j = 0; j < 4; ++j) Av[j] = as1[sv[j] * 2 + h];
#pragma unroll
        for (int j = 0; j < 4; ++j)
            Hv[j] = *(const uint2*)(h1p + (((size_t)(uint)sv[j]) << 7) + boff);
#pragma unroll
        for (int j = 0; j < 4; ++j) {
            float a = Av[j] + adv; a = a > 0.f ? a : 0.2f * a;
            float e = __expf(a);
            s += e;
            f32x2 ev = {e, e};
            ac01 += ev * __builtin_amdgcn_cvt_pk_f32_fp8((int)Hv[j].x, false);
            ac23 += ev * __builtin_amdgcn_cvt_pk_f32_fp8((int)Hv[j].x, true);
            ac45 += ev * __builtin_amdgcn_cvt_pk_f32_fp8((int)Hv[j].y, false);
            ac67 += ev * __builtin_amdgcn_cvt_pk_f32_fp8((int)Hv[j].y, true);
        }
    }
    for (; i < end; ++i) {
        int src = csr_src[i];
        float a = as1[src * 2 + h] + adv; a = a > 0.f ? a : 0.2f * a;
        float e = __expf(a);
        s += e;
        uint2 hv = *(const uint2*)(h1p + (((size_t)(uint)src) << 7) + boff);
        f32x2 ev = {e, e};
        ac01 += ev * __builtin_amdgcn_cvt_pk_f32_fp8((int)hv.x, false);
        ac23 += ev * __builtin_amdgcn_cvt_pk_f32_fp8((int)hv.x, true);
        ac45 += ev * __builtin_amdgcn_cvt_pk_f32_fp8((int)hv.y, false);
        ac67 += ev * __builtin_amdgcn_cvt_pk_f32_fp8((int)hv.y, true);
    }
    float inv = 1.f / (s + 1e-16f);

    // fused layer-2 input: v = relu(out1 + b1) in permuted order p = sl*8+j
    float4 bv0 = *(const float4*)&b1p[sl * 8];
    float4 bv1 = *(const float4*)&b1p[sl * 8 + 4];
    float v[8];
    v[0] = fmaxf(ac01[0] * inv + bv0.x, 0.f);
    v[1] = fmaxf(ac01[1] * inv + bv0.y, 0.f);
    v[2] = fmaxf(ac23[0] * inv + bv0.z, 0.f);
    v[3] = fmaxf(ac23[1] * inv + bv0.w, 0.f);
    v[4] = fmaxf(ac45[0] * inv + bv1.x, 0.f);
    v[5] = fmaxf(ac45[1] * inv + bv1.y, 0.f);
    v[6] = fmaxf(ac67[0] * inv + bv1.z, 0.f);
    v[7] = fmaxf(ac67[1] * inv + bv1.w, 0.f);

    // W2p rows sl*8 .. sl*8+7 = 56 contiguous floats
    float w2r[56];
    {
        const float4* wp = (const float4*)(W2p + sl * 56);
#pragma unroll
        for (int k = 0; k < 14; ++k) {
            float4 f = wp[k];
            w2r[4 * k + 0] = f.x; w2r[4 * k + 1] = f.y;
            w2r[4 * k + 2] = f.z; w2r[4 * k + 3] = f.w;
        }
    }
    float p[7];
#pragma unroll
    for (int j = 0; j < 7; ++j) p[j] = 0.f;
#pragma unroll
    for (int r = 0; r < 8; ++r)
#pragma unroll
        for (int j = 0; j < 7; ++j) p[j] += v[r] * w2r[r * 7 + j];
#pragma unroll
    for (int off = 1; off <= 8; off <<= 1)
#pragma unroll
        for (int j = 0; j < 7; ++j) p[j] += __shfl_xor(p[j], off, 64);

    if (sl == 0) {
        float asv = 0.f, adv2 = 0.f;
#pragma unroll
        for (int j = 0; j < 7; ++j) {
            h2p[(size_t)n * H2S + j] = p[j];
            asv += p[j] * a_src2[j];
            adv2 += p[j] * a_dst2[j];
        }
        h2p[(size_t)n * H2S + 7] = 0.f;
        as2[n] = asv; ad2[n] = adv2;
    }
}

// ---- Layer-2 aggregate + bias + log_softmax fused (4 lanes / node) ----------
__global__ __launch_bounds__(256) void k_aggr2ls(
    const int* __restrict__ rowptr, const int* __restrict__ csr_src,
    const float* __restrict__ as2, const float* __restrict__ ad2,
    const float* __restrict__ h2p, const float* __restrict__ b2,
    float* __restrict__ out, int N)
{
    int bid = xcd_swz(blockIdx.x, gridDim.x);
    int g = bid * 256 + (int)threadIdx.x;
    int n = g >> 2, l = g & 3;          // lane handles cols 2l, 2l+1 (col7=pad)
    if (n >= N) return;
    float adv = ad2[n];
    int beg = rowptr[n], end = rowptr[n + 1];
    f32x2 acc = {0.f, 0.f};
    float s = 0.f;
    int i = beg;
    for (; i + 4 <= end; i += 4) {
        int sv[4]; float Av[4]; float2 Hv[4];
#pragma unroll
        for (int j = 0; j < 4; ++j) sv[j] = csr_src[i + j];
#pragma unroll
        for (int j = 0; j < 4; ++j) Av[j] = as2[sv[j]];
#pragma unroll
        for (int j = 0; j < 4; ++j)
            Hv[j] = *(const float2*)(h2p + ((size_t)(uint)sv[j]) * H2S + 2 * l);
#pragma unroll
        for (int j = 0; j < 4; ++j) {
            float a = Av[j] + adv;
            a = a > 0.f ? a : 0.2f * a;
            float e = __expf(a);
            s += e;
            f32x2 ev = {e, e};
            f32x2 hv = {Hv[j].x, Hv[j].y};
            acc += ev * hv;
        }
    }
    for (; i < end; ++i) {
        int s0 = csr_src[i];
        float a = as2[s0] + adv;
        a = a > 0.f ? a : 0.2f * a;
        float e = __expf(a);
        s += e;
        float2 hv2 = *(const float2*)(h2p + ((size_t)(uint)s0) * H2S + 2 * l);
        f32x2 ev = {e, e};
        f32x2 hv = {hv2.x, hv2.y};
        acc += ev * hv;
    }
    float invs = 1.f / (s + 1e-16f);
    float va = acc[0] * invs + b2[2 * l];
    float vb = (2 * l + 1 < 7) ? acc[1] * invs + b2[2 * l + 1] : -1e30f;
    float m = fmaxf(va, vb);
#pragma unroll
    for (int off = 1; off <= 2; off <<= 1)
        m = fmaxf(m, __shfl_xor(m, off, 4));
    float ex = __expf(va - m) + ((2 * l + 1 < 7) ? __expf(vb - m) : 0.f);
#pragma unroll
    for (int off = 1; off <= 2; off <<= 1)
        ex += __shfl_xor(ex, off, 4);
    float lg = __logf(ex);
    out[(size_t)n * F_OUT + 2 * l] = va - m - lg;
    if (2 * l + 1 < 7) out[(size_t)n * F_OUT + 2 * l + 1] = vb - m - lg;
}

extern "C" void kernel_launch(void* const* d_in, const int* in_sizes, int n_in,
                              void* d_out, int out_size, void* d_ws, size_t ws_size,
                              hipStream_t stream) {
    const float* x      = (const float*)d_in[0];
    const int*   ei     = (const int*)d_in[1];   // [2,E] int32
    const float* W1     = (const float*)d_in[2];
    const float* a_src1 = (const float*)d_in[3];
    const float* a_dst1 = (const float*)d_in[4];
    const float* b1     = (const float*)d_in[5];
    const float* W2     = (const float*)d_in[6];
    const float* a_src2 = (const float*)d_in[7];
    const float* a_dst2 = (const float*)d_in[8];
    const float* b2     = (const float*)d_in[9];
    float* out = (float*)d_out;

    const int N    = in_sizes[0] / F_IN;
    const int E    = in_sizes[1] / 2;
    const int Etot = E + N;
    const int NB   = (N + BSZ - 1) >> BSH;          // buckets (196 for N=100k)
    const int NBIN = (Etot + BINCH - 1) / BINCH;

    char* ws = (char*)d_ws;
    size_t off = 0;
    auto A = [&](size_t bytes) -> void* {
        char* p = ws + off;
        off += (bytes + 255) & ~(size_t)255;
        return (void*)p;
    };
    ushort* Wsw    = (ushort*)A((size_t)128 * 128 * 2);
    float*  W2p    = (float*) A((size_t)128 * F_OUT * 4);
    float*  b1p    = (float*) A((size_t)128 * 4);
    unsigned char* h1p = (unsigned char*)A((size_t)N * HC);
    float*  as1    = (float*) A((size_t)N * 2 * 4);
    float*  ad1    = (float*) A((size_t)N * 2 * 4);
    int*    rowptr = (int*)   A((size_t)(N + 1) * 4);
    int*    csr    = (int*)   A((size_t)Etot * 4);
    int*    bcnt   = (int*)   A(256 * 4);
    // binned overlays {h2p, as2, ad2}: binned dead after fill phase.
    uint*   binned = (uint*)  A((size_t)NB * BCAP * 4);
    float*  h2p    = (float*)binned;
    float*  as2    = (float*)((char*)binned + (((size_t)N * H2S * 4 + 255) & ~(size_t)255));
    float*  ad2    = (float*)((char*)as2 + (((size_t)N * 4 + 255) & ~(size_t)255));

    k_cvt<<<65, 256, 0, stream>>>(W1, Wsw, W2, b1, W2p, b1p, bcnt);
    k_bingemm<<<NBIN + (N + 63) / 64, 256, 0, stream>>>(
        ei, E, Etot, NBIN, bcnt, binned,
        x, Wsw, a_src1, a_dst1, h1p, as1, ad1, N);
    k_fill<<<NB, 256, 0, stream>>>(binned, bcnt, rowptr, csr, N, NB);
    k_aggr1_l2<<<(N + 15) / 16, 256, 0, stream>>>(rowptr, csr, as1, ad1, h1p,
                                                  b1p, W2p, a_src2, a_dst2,
                                                  h2p, as2, ad2, N);
    k_aggr2ls<<<((size_t)N * 4 + 255) / 256, 256, 0, stream>>>(rowptr, csr,
                                                               as2, ad2, h2p, b2, out, N);
}

// Round 16
// 134.565 us; speedup vs baseline: 1.3103x; 1.0812x over previous
//
#include <hip/hip_runtime.h>
#include <hip/hip_bf16.h>

#define F_IN 128
#define HC   128   // H1*C1
#define C1   64
#define F_OUT 7
#define H2S  8      // padded h2 row stride; slot 7 carries as2
#define BSH  9      // 512 nodes per bucket
#define BSZ  512
#define BINCH 4096  // edges per WG in binning (16/thread, single pass)
#define BCAP 12288  // bucket region capacity (mean ~8700, +~17 sigma)

typedef __attribute__((ext_vector_type(8))) short short8;
typedef __attribute__((ext_vector_type(4))) float f32x4;
typedef __attribute__((ext_vector_type(2))) float f32x2;

__device__ __forceinline__ ushort f2bf(float f) {
    uint u = __builtin_bit_cast(uint, f);
    u = (u + 0x7FFFu + ((u >> 16) & 1u)) >> 16;   // RNE
    return (ushort)u;
}

// fp8-permuted layout: byte b = h*64 + lr*4 + jj  <->  col c = 16*(4*h+jj) + lr
__device__ __forceinline__ int perm_col(int p_byte) {
    int slp = p_byte >> 3, j = p_byte & 7;
    int h = slp >> 3, sg = slp & 7;
    int lr = 2 * sg + (j >> 2), jj = j & 3;
    return 16 * (4 * h + jj) + lr;
}

// ---- k_cvt: blocks [0,64) W1 -> bf16 transposed+swizzled; [64] W2p/b1p+bcnt -
__global__ __launch_bounds__(256) void k_cvt(
    const float* __restrict__ W1, ushort* __restrict__ Wsw,
    const float* __restrict__ W2, const float* __restrict__ b1,
    float* __restrict__ W2p, float* __restrict__ b1p, int* __restrict__ bcnt)
{
    int b = blockIdx.x, t = threadIdx.x;
    if (b < 64) {
        int i = b * 256 + t;                // 0..16383
        int k = i >> 7, n = i & 127;
        float v = W1[k * HC + n];
        int idx = n * 128 + (((k & ~7) ^ ((n & 7) << 3)) | (k & 7));
        Wsw[idx] = f2bf(v);
    } else {
        bcnt[t] = 0;
        for (int i = t; i < 128 * F_OUT; i += 256) {
            int p = i / F_OUT, o = i - p * F_OUT;
            W2p[i] = W2[perm_col(p) * F_OUT + o];
        }
        if (t < 128) b1p[t] = b1[perm_col(t)];
    }
}

// ---- k_bingemm: blocks [0,NBIN) edge binning (single ei pass, reg-held);
//                 [NBIN,...) GEMM1 MFMA --------------------------------------
__global__ __launch_bounds__(256) void k_bingemm(
    const int* __restrict__ ei, int E, int Etot, int NBIN,
    int* __restrict__ bcnt, uint* __restrict__ binned,
    const float* __restrict__ x, const ushort* __restrict__ Wsw,
    const float* __restrict__ a_src, const float* __restrict__ a_dst,
    unsigned char* __restrict__ h1p, float* __restrict__ as1, float* __restrict__ ad1,
    int N)
{
    __shared__ __align__(16) char smem[128 * 128 * 2];
    const int t = threadIdx.x;

    if ((int)blockIdx.x < NBIN) {
        // ---------------- edge binning: one pass, 16 edges/thread in regs ---
        int* hist = (int*)smem;          // [256]
        int* base = hist + 256;          // [256]
        hist[t] = 0;
        __syncthreads();
        long c0 = (long)blockIdx.x * BINCH;
        uint val[16]; int bkt[16];
#pragma unroll
        for (int i2 = 0; i2 < 16; ++i2) {
            long e = c0 + t + i2 * 256;
            int s = 0, d = 0;
            bkt[i2] = -1;
            if (e < Etot) {
                if (e < E) { s = ei[e]; d = ei[E + e]; } else { s = (int)(e - E); d = s; }
                bkt[i2] = d >> BSH;
                atomicAdd(&hist[bkt[i2]], 1);
            }
            val[i2] = ((uint)s << BSH) | (uint)(d & (BSZ - 1));
        }
        __syncthreads();
        base[t] = t * BCAP + ((hist[t] > 0) ? atomicAdd(&bcnt[t], hist[t]) : 0);
        __syncthreads();
#pragma unroll
        for (int i2 = 0; i2 < 16; ++i2) {
            if (bkt[i2] >= 0) {
                int pos = atomicAdd(&base[bkt[i2]], 1);
                if (pos < (bkt[i2] + 1) * BCAP)   // overflow guard
                    binned[pos] = val[i2];
            }
        }
    } else {
        // ---------------- GEMM1 (bf16 MFMA, fused alphas, fp8 h1 out) -------
        ushort* Bs = (ushort*)smem;     // pre-swizzled [n][k] bf16
        const int w = t >> 6, l = t & 63;
        const int lr = l & 15, hi = l >> 4;
        const int n0 = (blockIdx.x - NBIN) * 64;

        {
            const uint4* src = (const uint4*)Wsw;
            uint4* dst = (uint4*)Bs;
#pragma unroll
            for (int it = 0; it < 8; ++it) dst[t + it * 256] = src[t + it * 256];
        }
        __syncthreads();

        f32x4 acc[8];
#pragma unroll
        for (int j = 0; j < 8; ++j) acc[j] = (f32x4){0.f, 0.f, 0.f, 0.f};

        int arow = n0 + w * 16 + lr;
        if (arow >= N) arow = N - 1;
        const float* aptr = x + (size_t)arow * F_IN + hi * 8;

#pragma unroll
        for (int kt = 0; kt < 4; ++kt) {
            float4 f0 = *(const float4*)(aptr + kt * 32);
            float4 f1 = *(const float4*)(aptr + kt * 32 + 4);
            short8 a;
            a[0] = (short)f2bf(f0.x); a[1] = (short)f2bf(f0.y);
            a[2] = (short)f2bf(f0.z); a[3] = (short)f2bf(f0.w);
            a[4] = (short)f2bf(f1.x); a[5] = (short)f2bf(f1.y);
            a[6] = (short)f2bf(f1.z); a[7] = (short)f2bf(f1.w);
#pragma unroll
            for (int j = 0; j < 8; ++j) {
                int rn = 16 * j + lr;
                int kidx = (kt * 32 + hi * 8) ^ ((rn & 7) << 3);
                short8 b = *(const short8*)(Bs + rn * 128 + kidx);
                acc[j] = __builtin_amdgcn_mfma_f32_16x16x32_bf16(a, b, acc[j], 0, 0, 0);
            }
        }

        float as_[8], ad_[8];
#pragma unroll
        for (int j = 0; j < 8; ++j) {
            int hd = j >> 2;
            int c = 16 * (j & 3) + lr;
            as_[j] = a_src[hd * C1 + c];
            ad_[j] = a_dst[hd * C1 + c];
        }
#pragma unroll
        for (int i = 0; i < 4; ++i) {
            int r = n0 + w * 16 + hi * 4 + i;
            float ps0 = 0, ps1 = 0, pd0 = 0, pd1 = 0;
#pragma unroll
            for (int j = 0; j < 4; ++j) { ps0 += acc[j][i] * as_[j]; pd0 += acc[j][i] * ad_[j]; }
#pragma unroll
            for (int j = 4; j < 8; ++j) { ps1 += acc[j][i] * as_[j]; pd1 += acc[j][i] * ad_[j]; }
#pragma unroll
            for (int off = 1; off <= 8; off <<= 1) {
                ps0 += __shfl_xor(ps0, off, 64);
                ps1 += __shfl_xor(ps1, off, 64);
                pd0 += __shfl_xor(pd0, off, 64);
                pd1 += __shfl_xor(pd1, off, 64);
            }
            if (r < N) {
                // head-split fp8 layout: head0 word at byte lr*4, head1 at 64+lr*4
                int w0 = 0, w1 = 0;
                w0 = __builtin_amdgcn_cvt_pk_fp8_f32(acc[0][i], acc[1][i], w0, false);
                w0 = __builtin_amdgcn_cvt_pk_fp8_f32(acc[2][i], acc[3][i], w0, true);
                w1 = __builtin_amdgcn_cvt_pk_fp8_f32(acc[4][i], acc[5][i], w1, false);
                w1 = __builtin_amdgcn_cvt_pk_fp8_f32(acc[6][i], acc[7][i], w1, true);
                *(uint*)(h1p + (size_t)r * HC + lr * 4)      = (uint)w0;
                *(uint*)(h1p + (size_t)r * HC + 64 + lr * 4) = (uint)w1;
                if (lr == 0) {
                    as1[r * 2 + 0] = ps0; as1[r * 2 + 1] = ps1;
                    ad1[r * 2 + 0] = pd0; ad1[r * 2 + 1] = pd1;
                }
            }
        }
    }
}

// ---- k_fill: per-bucket CSR fine fill ---------------------------------------
__global__ __launch_bounds__(256) void k_fill(
    const uint* __restrict__ binned, const int* __restrict__ bcnt,
    int* __restrict__ rowptr, int* __restrict__ csr, int N, int NB)
{
    __shared__ int deg[BSZ];
    __shared__ int cur[BSZ];
    __shared__ int sc[256];
    int b = blockIdx.x, t = threadIdx.x;
    int cv = (t < NB) ? min(bcnt[t], BCAP) : 0;
    sc[t] = cv;
    __syncthreads();
    for (int off = 1; off < 256; off <<= 1) {
        int u = (t >= off) ? sc[t - off] : 0;
        __syncthreads();
        sc[t] += u;
        __syncthreads();
    }
    int total = sc[255];
    int s0 = (b > 0) ? sc[b - 1] : 0;
    int cntb = min(bcnt[b], BCAP);
    __syncthreads();

    int n0 = b << BSH;
    int nn = N - n0; if (nn > BSZ) nn = BSZ;
    deg[t] = 0; deg[t + 256] = 0;
    __syncthreads();
    const uint* bb = binned + (size_t)b * BCAP;
    for (int i = t; i < cntb; i += 256)
        atomicAdd(&deg[bb[i] & (BSZ - 1)], 1);
    __syncthreads();
    int d0 = deg[2 * t], d1 = deg[2 * t + 1];
    int ts = d0 + d1;
    sc[t] = ts;
    __syncthreads();
    for (int off = 1; off < 256; off <<= 1) {
        int u = (t >= off) ? sc[t - off] : 0;
        __syncthreads();
        sc[t] += u;
        __syncthreads();
    }
    int ex = sc[t] - ts + s0;
    if (2 * t < nn)     { rowptr[n0 + 2 * t]     = ex;      cur[2 * t]     = ex; }
    if (2 * t + 1 < nn) { rowptr[n0 + 2 * t + 1] = ex + d0; cur[2 * t + 1] = ex + d0; }
    __syncthreads();
    for (int i = t; i < cntb; i += 256) {
        uint en = bb[i];
        int pos = atomicAdd(&cur[en & (BSZ - 1)], 1);
        csr[pos] = (int)(en >> BSH);
    }
    if (b == 0 && t == 0) rowptr[N] = total;
}

// ---- Layer-1 aggregate (fp8, head-split) + fused bias/ReLU/GEMM2/alpha2 -----
// 16 lanes per node, natural order (R12 shape). as2 fused into h2p slot 7.
__global__ __launch_bounds__(256) void k_aggr1_l2(
    const int* __restrict__ rowptr, const int* __restrict__ csr_src,
    const float* __restrict__ as1, const float* __restrict__ ad1,
    const unsigned char* __restrict__ h1p, const float* __restrict__ b1p,
    const float* __restrict__ W2p, const float* __restrict__ a_src2,
    const float* __restrict__ a_dst2,
    float* __restrict__ h2p, float* __restrict__ ad2,
    int N)
{
    int w = threadIdx.x >> 6, l = threadIdx.x & 63;
    int q = l >> 4, sl = l & 15;
    int n = blockIdx.x * 16 + w * 4 + q;
    if (n >= N) return;
    const int h = sl >> 3;                 // this lane's head
    const int boff = sl * 8;               // byte offset within row
    float adv = ad1[n * 2 + h];
    int beg = rowptr[n], end = rowptr[n + 1];
    f32x2 ac01 = {0.f, 0.f}, ac23 = {0.f, 0.f}, ac45 = {0.f, 0.f}, ac67 = {0.f, 0.f};
    float s = 0.f;

    int i = beg;
    for (; i + 4 <= end; i += 4) {
        int sv[4]; float Av[4]; uint2 Hv[4];
#pragma unroll
        for (int j = 0; j < 4; ++j) sv[j] = csr_src[i + j];
#pragma unroll
        for (int j = 0; j < 4; ++j) Av[j] = as1[sv[j] * 2 + h];
#pragma unroll
        for (int j = 0; j < 4; ++j)
            Hv[j] = *(const uint2*)(h1p + (((size_t)(uint)sv[j]) << 7) + boff);
#pragma unroll
        for (int j = 0; j < 4; ++j) {
            float a = Av[j] + adv; a = a > 0.f ? a : 0.2f * a;
            float e = __expf(a);
            s += e;
            f32x2 ev = {e, e};
            ac01 += ev * __builtin_amdgcn_cvt_pk_f32_fp8((int)Hv[j].x, false);
            ac23 += ev * __builtin_amdgcn_cvt_pk_f32_fp8((int)Hv[j].x, true);
            ac45 += ev * __builtin_amdgcn_cvt_pk_f32_fp8((int)Hv[j].y, false);
            ac67 += ev * __builtin_amdgcn_cvt_pk_f32_fp8((int)Hv[j].y, true);
        }
    }
    for (; i < end; ++i) {
        int src = csr_src[i];
        float a = as1[src * 2 + h] + adv; a = a > 0.f ? a : 0.2f * a;
        float e = __expf(a);
        s += e;
        uint2 hv = *(const uint2*)(h1p + (((size_t)(uint)src) << 7) + boff);
        f32x2 ev = {e, e};
        ac01 += ev * __builtin_amdgcn_cvt_pk_f32_fp8((int)hv.x, false);
        ac23 += ev * __builtin_amdgcn_cvt_pk_f32_fp8((int)hv.x, true);
        ac45 += ev * __builtin_amdgcn_cvt_pk_f32_fp8((int)hv.y, false);
        ac67 += ev * __builtin_amdgcn_cvt_pk_f32_fp8((int)hv.y, true);
    }
    float inv = 1.f / (s + 1e-16f);

    // fused layer-2 input: v = relu(out1 + b1) in permuted order p = sl*8+j
    float4 bv0 = *(const float4*)&b1p[sl * 8];
    float4 bv1 = *(const float4*)&b1p[sl * 8 + 4];
    float v[8];
    v[0] = fmaxf(ac01[0] * inv + bv0.x, 0.f);
    v[1] = fmaxf(ac01[1] * inv + bv0.y, 0.f);
    v[2] = fmaxf(ac23[0] * inv + bv0.z, 0.f);
    v[3] = fmaxf(ac23[1] * inv + bv0.w, 0.f);
    v[4] = fmaxf(ac45[0] * inv + bv1.x, 0.f);
    v[5] = fmaxf(ac45[1] * inv + bv1.y, 0.f);
    v[6] = fmaxf(ac67[0] * inv + bv1.z, 0.f);
    v[7] = fmaxf(ac67[1] * inv + bv1.w, 0.f);

    // W2p rows sl*8 .. sl*8+7 = 56 contiguous floats
    float w2r[56];
    {
        const float4* wp = (const float4*)(W2p + sl * 56);
#pragma unroll
        for (int k = 0; k < 14; ++k) {
            float4 f = wp[k];
            w2r[4 * k + 0] = f.x; w2r[4 * k + 1] = f.y;
            w2r[4 * k + 2] = f.z; w2r[4 * k + 3] = f.w;
        }
    }
    float p[7];
#pragma unroll
    for (int j = 0; j < 7; ++j) p[j] = 0.f;
#pragma unroll
    for (int r = 0; r < 8; ++r)
#pragma unroll
        for (int j = 0; j < 7; ++j) p[j] += v[r] * w2r[r * 7 + j];
#pragma unroll
    for (int off = 1; off <= 8; off <<= 1)
#pragma unroll
        for (int j = 0; j < 7; ++j) p[j] += __shfl_xor(p[j], off, 64);

    if (sl == 0) {
        float asv = 0.f, adv2 = 0.f;
#pragma unroll
        for (int j = 0; j < 7; ++j) {
            h2p[(size_t)n * H2S + j] = p[j];
            asv += p[j] * a_src2[j];
            adv2 += p[j] * a_dst2[j];
        }
        h2p[(size_t)n * H2S + 7] = asv;   // as2 fused into row slot 7
        ad2[n] = adv2;
    }
}

// ---- Layer-2 aggregate + bias + log_softmax fused (4 lanes / node) ----------
// as2 comes from h2p slot 7 (lane 3's float2.y), broadcast via shfl width-4.
__global__ __launch_bounds__(256) void k_aggr2ls(
    const int* __restrict__ rowptr, const int* __restrict__ csr_src,
    const float* __restrict__ ad2,
    const float* __restrict__ h2p, const float* __restrict__ b2,
    float* __restrict__ out, int N)
{
    int g = blockIdx.x * blockDim.x + threadIdx.x;
    int n = g >> 2, l = g & 2 | (g & 1);  // = g & 3
    l = g & 3;
    if (n >= N) return;
    float adv = ad2[n];
    int beg = rowptr[n], end = rowptr[n + 1];
    f32x2 acc = {0.f, 0.f};
    float s = 0.f;
    int i = beg;
    for (; i + 4 <= end; i += 4) {
        int sv[4]; float2 Hv[4];
#pragma unroll
        for (int j = 0; j < 4; ++j) sv[j] = csr_src[i + j];
#pragma unroll
        for (int j = 0; j < 4; ++j)
            Hv[j] = *(const float2*)(h2p + ((size_t)(uint)sv[j]) * H2S + 2 * l);
#pragma unroll
        for (int j = 0; j < 4; ++j) {
            float as2v = __shfl(Hv[j].y, 3, 4);   // lane3's col7 = as2[src]
            float a = as2v + adv;
            a = a > 0.f ? a : 0.2f * a;
            float e = __expf(a);
            s += e;
            f32x2 ev = {e, e};
            f32x2 hv = {Hv[j].x, Hv[j].y};
            acc += ev * hv;
        }
    }
    for (; i < end; ++i) {
        int s0 = csr_src[i];
        float2 hv2 = *(const float2*)(h2p + ((size_t)(uint)s0) * H2S + 2 * l);
        float as2v = __shfl(hv2.y, 3, 4);
        float a = as2v + adv;
        a = a > 0.f ? a : 0.2f * a;
        float e = __expf(a);
        s += e;
        f32x2 ev = {e, e};
        f32x2 hv = {hv2.x, hv2.y};
        acc += ev * hv;
    }
    float invs = 1.f / (s + 1e-16f);
    float va = acc[0] * invs + b2[2 * l];
    float vb = (2 * l + 1 < 7) ? acc[1] * invs + b2[2 * l + 1] : -1e30f;
    float m = fmaxf(va, vb);
#pragma unroll
    for (int off = 1; off <= 2; off <<= 1)
        m = fmaxf(m, __shfl_xor(m, off, 4));
    float ex = __expf(va - m) + ((2 * l + 1 < 7) ? __expf(vb - m) : 0.f);
#pragma unroll
    for (int off = 1; off <= 2; off <<= 1)
        ex += __shfl_xor(ex, off, 4);
    float lg = __logf(ex);
    out[(size_t)n * F_OUT + 2 * l] = va - m - lg;
    if (2 * l + 1 < 7) out[(size_t)n * F_OUT + 2 * l + 1] = vb - m - lg;
}

extern "C" void kernel_launch(void* const* d_in, const int* in_sizes, int n_in,
                              void* d_out, int out_size, void* d_ws, size_t ws_size,
                              hipStream_t stream) {
    const float* x      = (const float*)d_in[0];
    const int*   ei     = (const int*)d_in[1];   // [2,E] int32
    const float* W1     = (const float*)d_in[2];
    const float* a_src1 = (const float*)d_in[3];
    const float* a_dst1 = (const float*)d_in[4];
    const float* b1     = (const float*)d_in[5];
    const float* W2     = (const float*)d_in[6];
    const float* a_src2 = (const float*)d_in[7];
    const float* a_dst2 = (const float*)d_in[8];
    const float* b2     = (const float*)d_in[9];
    float* out = (float*)d_out;

    const int N    = in_sizes[0] / F_IN;
    const int E    = in_sizes[1] / 2;
    const int Etot = E + N;
    const int NB   = (N + BSZ - 1) >> BSH;          // buckets (196 for N=100k)
    const int NBIN = (Etot + BINCH - 1) / BINCH;

    char* ws = (char*)d_ws;
    size_t off = 0;
    auto A = [&](size_t bytes) -> void* {
        char* p = ws + off;
        off += (bytes + 255) & ~(size_t)255;
        return (void*)p;
    };
    ushort* Wsw    = (ushort*)A((size_t)128 * 128 * 2);
    float*  W2p    = (float*) A((size_t)128 * F_OUT * 4);
    float*  b1p    = (float*) A((size_t)128 * 4);
    unsigned char* h1p = (unsigned char*)A((size_t)N * HC);
    float*  as1    = (float*) A((size_t)N * 2 * 4);
    float*  ad1    = (float*) A((size_t)N * 2 * 4);
    int*    rowptr = (int*)   A((size_t)(N + 1) * 4);
    int*    csr    = (int*)   A((size_t)Etot * 4);
    int*    bcnt   = (int*)   A(256 * 4);
    // binned overlays {h2p, ad2}: binned dead after fill phase.
    uint*   binned = (uint*)  A((size_t)NB * BCAP * 4);
    float*  h2p    = (float*)binned;
    float*  ad2    = (float*)((char*)binned + (((size_t)N * H2S * 4 + 255) & ~(size_t)255));

    k_cvt<<<65, 256, 0, stream>>>(W1, Wsw, W2, b1, W2p, b1p, bcnt);
    k_bingemm<<<NBIN + (N + 63) / 64, 256, 0, stream>>>(
        ei, E, Etot, NBIN, bcnt, binned,
        x, Wsw, a_src1, a_dst1, h1p, as1, ad1, N);
    k_fill<<<NB, 256, 0, stream>>>(binned, bcnt, rowptr, csr, N, NB);
    k_aggr1_l2<<<(N + 15) / 16, 256, 0, stream>>>(rowptr, csr, as1, ad1, h1p,
                                                  b1p, W2p, a_src2, a_dst2,
                                                  h2p, ad2, N);
    k_aggr2ls<<<((size_t)N * 4 + 255) / 256, 256, 0, stream>>>(rowptr, csr,
                                                               ad2, h2p, b2, out, N);
}